// Round 10
// baseline (114.342 us; speedup 1.0000x reference)
//
#include <hip/hip_runtime.h>
#include <hip/hip_bf16.h>
#include <stdint.h>

// ---------------------------------------------------------------------------
// Head: out = softmax((x Wq)(x Wk)^T / 8) (x Wv)
// B=8, T=2048, C=512, D=64.  ALL I/O FP32; internals bf16 MFMA + fp32 accum.
//
// R10: proj W through LDS. R9 post-mortem: 2-tile proj waves halved wave
// count (12->6 waves/CU) and regressed; W-reuse must not cost occupancy.
// Now: block = ONE matrix x 4 token tiles; W (64 KB, already lane-linear
// frag-order) staged ONCE per block via global_load_lds width=16, all 4
// waves read W-frags with ds_read_b128 (lane stride 16B = 2-way bank = free).
// W L2 traffic 192->48 MB; W leaves the TA/L1 path. 768 blocks x 256 thr,
// 3072 waves (12/CU), LDS 64 KB -> 2 blocks/CU.
// attn/prep unchanged from R9 (2-q-tile waves, V-hoist, no-max softmax).
//
// MFMA 16x16x32 bf16 fragment maps (gfx950, m89/m91-verified):
//   A: lane holds A[m=lane&15][k=quad*8+j]   (quad=lane>>4, j=0..7)
//   B: lane holds B[k=quad*8+j][n=lane&15]
//   D: lane holds D[row=quad*4+r][col=lane&15] (r=reg 0..3)
//
// Fragment-order chunk layouts (16B chunks, chunk's 8 elems = j=0..7):
//   xb2: chunk[((tt*16+ks)*4+quad)*16+c] = x[tt*16+c][ks*32+quad*8+j]
//   wt2: chunk[(((w*4+mt)*16+ks)*4+quad)*16+c] = W_w[ks*32+quad*8+j][mt*16+c]
//   kg2: chunk[b*16384 + ((g*2+h)*4+quad)*16+c] = K[b][g*16+c][h*32+quad*8+j]
//   vg2: chunk[b*16384 + ((s*4+mt)*4+quad)*16+c] = V[b][s*32+quad*8+j][mt*16+c]
// ---------------------------------------------------------------------------

typedef short bf16x8 __attribute__((ext_vector_type(8)));
typedef float f32x4 __attribute__((ext_vector_type(4)));

#define MFMA_BF16 __builtin_amdgcn_mfma_f32_16x16x32_bf16

__device__ __forceinline__ unsigned int pk2(float a, float b) {
    __hip_bfloat162 h = __float22bfloat162_rn(float2{a, b});   // v_cvt_pk_bf16_f32
    union { __hip_bfloat162 h; unsigned int u; } r; r.h = h;
    return r.u;
}

__device__ __forceinline__ uint2 pack4_bf16(float a, float b, float c, float d) {
    uint2 r; r.x = pk2(a, b); r.y = pk2(c, d); return r;
}

__device__ __forceinline__ bf16x8 cvt8(f32x4 a, f32x4 b) {
    union { bf16x8 v; unsigned int u[4]; } r;
    r.u[0] = pk2(a[0], a[1]); r.u[1] = pk2(a[2], a[3]);
    r.u[2] = pk2(b[0], b[1]); r.u[3] = pk2(b[2], b[3]);
    return r.v;
}

__device__ __forceinline__ unsigned short bf1(float a) {
    __hip_bfloat16 h = __float2bfloat16(a);
    union { __hip_bfloat16 h; unsigned short u; } r; r.h = h;
    return r.u;
}

// ---------------------------------------------------------------------------
// Kernel 0: prep = wt (blocks 0..47) + xconv (blocks 48..4143).
// ---------------------------------------------------------------------------
__global__ void prep_kernel(const float* __restrict__ x,
                            const float* __restrict__ Wq,
                            const float* __restrict__ Wk,
                            const float* __restrict__ Wv,
                            unsigned short* __restrict__ xb2,
                            unsigned short* __restrict__ wt2)
{
    if (blockIdx.x < 48) {
        int id = blockIdx.x * 256 + threadIdx.x;      // 12288 = 3*4*16*4*16
        int c    = id & 15;
        int quad = (id >> 4) & 3;
        int ks   = (id >> 6) & 15;
        int mt   = (id >> 10) & 3;
        int w    = id >> 12;
        const float* src = (w == 0) ? Wq : ((w == 1) ? Wk : Wv);
        const int n  = mt * 16 + c;
        const int k0 = ks * 32 + quad * 8;
        unsigned short* dst = wt2 + (size_t)id * 8;
        #pragma unroll
        for (int j = 0; j < 8; j++)
            dst[j] = bf1(src[(size_t)(k0 + j) * 64 + n]);
        return;
    }
    int i = (blockIdx.x - 48) * 256 + threadIdx.x;    // i = tok*64 + dblock
    int tok    = i >> 6;
    int dblock = i & 63;
    f32x4 a = *(const f32x4*)(x + (size_t)i * 8);
    f32x4 b = *(const f32x4*)(x + (size_t)i * 8 + 4);
    int tt = tok >> 4, c = tok & 15;
    int ks = dblock >> 2, quad = dblock & 3;
    size_t chunk = ((size_t)(tt * 16 + ks) * 4 + quad) * 16 + c;
    *(bf16x8*)(xb2 + chunk * 8) = cvt8(a, b);
}

// ---------------------------------------------------------------------------
// Kernel 1: projections, W staged in LDS. Block = one matrix x 4 token
// tiles; W staged once per block (64 global_load_lds dwordx4, 16/wave),
// K-loop reads W via ds_read_b128. x frags stream from global as before.
// 768 blocks x 256 threads = 3072 waves.
// ---------------------------------------------------------------------------
__global__ __launch_bounds__(256, 1) void proj_kernel(
    const unsigned short* __restrict__ xb2, const unsigned short* __restrict__ wt2,
    unsigned short* __restrict__ qg, unsigned short* __restrict__ kg2,
    unsigned short* __restrict__ vg2)
{
    __shared__ unsigned short wlds[4096 * 8];     // 64 KB: one matrix, frag-order

    const int lane = threadIdx.x & 63;
    const int c    = lane & 15;
    const int quad = lane >> 4;
    const int wave = threadIdx.x >> 6;
    const int w    = blockIdx.x % 3;              // matrix: 0:q 1:k 2:v
    const int tt   = (blockIdx.x / 3) * 4 + wave; // token tile 0..1023
    const int t0   = tt * 16;

    // ---- stage W: wave v loads chunks [v*1024 + i*64 + lane], i=0..15 ----
    {
        const unsigned short* wsrc = wt2 + ((size_t)w * 4096 + wave * 1024 + lane) * 8;
        unsigned short* ldst = &wlds[(size_t)(wave * 1024) * 8];
        #pragma unroll
        for (int i = 0; i < 16; i++) {
            __builtin_amdgcn_global_load_lds(
                (const __attribute__((address_space(1))) unsigned int*)(wsrc + (size_t)i * 64 * 8),
                (__attribute__((address_space(3))) unsigned int*)(ldst + (size_t)i * 64 * 8),
                16, 0, 0);
        }
    }
    __syncthreads();

    f32x4 acc[4];
    #pragma unroll
    for (int i = 0; i < 4; i++) acc[i] = f32x4{0.f, 0.f, 0.f, 0.f};

    const unsigned short* xbase = xb2 + ((size_t)tt * 1024 + lane) * 8;
    const unsigned short* wbase = &wlds[(size_t)lane * 8];

    #pragma unroll 4
    for (int ks = 0; ks < 16; ks++) {
        bf16x8 xf = *(const bf16x8*)(xbase + (size_t)ks * 512);
        #pragma unroll
        for (int mt = 0; mt < 4; mt++) {
            bf16x8 wa = *(const bf16x8*)(wbase + ((size_t)mt * 16 + ks) * 512);
            acc[mt] = MFMA_BF16(wa, xf, acc[mt], 0, 0, 0);
        }
    }

    const int b  = t0 >> 11;             // batch
    const int tb = t0 & 2047;            // batch-local tile base

    if (w == 0) {
        unsigned short* base = qg + (size_t)(t0 + c) * 64;
        #pragma unroll
        for (int mt = 0; mt < 4; mt++)
            *(uint2*)(base + mt * 16 + quad * 4) =
                pack4_bf16(acc[mt][0], acc[mt][1], acc[mt][2], acc[mt][3]);
    } else if (w == 1) {
        const int g = tb >> 4;
        #pragma unroll
        for (int mt = 0; mt < 4; mt++) {
            const int h  = mt >> 1;
            const int qk = (mt & 1) * 2 + (quad >> 1);
            size_t chunk = (size_t)b * 16384 + ((size_t)(g * 2 + h) * 4 + qk) * 16 + c;
            *(uint2*)(kg2 + chunk * 8 + (quad & 1) * 4) =
                pack4_bf16(acc[mt][0], acc[mt][1], acc[mt][2], acc[mt][3]);
        }
    } else {
        const int tk = tb + c;
        const int s  = tk >> 5;
        const int qv = (tk >> 3) & 3;
        const int j  = tk & 7;
        #pragma unroll
        for (int mt = 0; mt < 4; mt++) {
            size_t chunk = (size_t)b * 16384 + ((size_t)(s * 4 + mt) * 4 + qv) * 16 + quad * 4;
            unsigned short* dst = vg2 + chunk * 8 + j;
            dst[0]  = bf1(acc[mt][0]);
            dst[8]  = bf1(acc[mt][1]);
            dst[16] = bf1(acc[mt][2]);
            dst[24] = bf1(acc[mt][3]);
        }
    }
}

// ---------------------------------------------------------------------------
// Kernel 2: flash attention, 2 q-tiles per wave (in-wave KV reuse), V loads
// hoisted ahead of the S MFMAs. 512 blocks x 256 threads. (R9 unchanged.)
// ---------------------------------------------------------------------------
__global__ __launch_bounds__(256, 1) void attn_kernel(
    const unsigned short* __restrict__ qg, const unsigned short* __restrict__ kg2,
    const unsigned short* __restrict__ vg2, float* __restrict__ out)
{
    __shared__ unsigned short pt[4][2][16 * 136];  // [wave][qtile][q][key]
    __shared__ float obuf[4][2][16][68];           // [wave][qtile][q][d]
    __shared__ float lbuf[4][2][16];

    const int lane = threadIdx.x & 63;
    const int wave = threadIdx.x >> 6;
    const int c    = lane & 15;
    const int quad = lane >> 4;
    const int b    = blockIdx.x & 7;             // batch -> XCD (L2 locality)
    const int g    = blockIdx.x >> 3;            // 32-row group (0..63)
    const int tb   = b * 2048 + g * 32;          // block q base

    unsigned short* ptw = &pt[wave][0][0];
    const unsigned short* kbase = kg2 + ((size_t)b * 16384 + lane) * 8;
    const unsigned short* vbase = vg2 + ((size_t)b * 16384 + lane) * 8;

    // Q frags for both q-tiles
    bf16x8 qa0 = *(const bf16x8*)(qg + (size_t)(tb + c) * 64 + quad * 8);
    bf16x8 qa1 = *(const bf16x8*)(qg + (size_t)(tb + c) * 64 + 32 + quad * 8);
    bf16x8 qc0 = *(const bf16x8*)(qg + (size_t)(tb + 16 + c) * 64 + quad * 8);
    bf16x8 qc1 = *(const bf16x8*)(qg + (size_t)(tb + 16 + c) * 64 + 32 + quad * 8);

    f32x4 oa0 = {0,0,0,0}, oa1 = {0,0,0,0}, oa2 = {0,0,0,0}, oa3 = {0,0,0,0};
    f32x4 ob0 = {0,0,0,0}, ob1 = {0,0,0,0}, ob2 = {0,0,0,0}, ob3 = {0,0,0,0};
    f32x4 laccA = {0,0,0,0}, laccB = {0,0,0,0};
    const float cexp = 0.18033688011112042f;   // log2(e)/8  (scores = raw/8)

    for (int kt = wave * 4; kt < wave * 4 + 4; kt++) {
        const int key0 = kt * 128;
        const int g0   = key0 >> 4;              // 16-key group base
        const int s0   = key0 >> 5;              // 32-key block base

        // ---- V ks=0,1 preloads FIRST: latency hides under S MFMAs + exp ----
        bf16x8 va[2][4];
        #pragma unroll
        for (int mt = 0; mt < 4; mt++) {
            va[0][mt] = *(const bf16x8*)(vbase + (size_t)((s0    ) * 4 + mt) * 64 * 8);
            va[1][mt] = *(const bf16x8*)(vbase + (size_t)((s0 + 1) * 4 + mt) * 64 * 8);
        }

        // ---- S^T = K·Q^T for BOTH q-tiles; K frags loaded once ----
        f32x4 stA[8], stB[8];
        const f32x4 z = {0,0,0,0};
        #pragma unroll
        for (int mt = 0; mt < 8; mt++) {
            bf16x8 k0 = *(const bf16x8*)(kbase + (size_t)((g0 + mt) * 2    ) * 64 * 8);
            bf16x8 k1 = *(const bf16x8*)(kbase + (size_t)((g0 + mt) * 2 + 1) * 64 * 8);
            stA[mt] = MFMA_BF16(k0, qa0, z, 0, 0, 0);
            stA[mt] = MFMA_BF16(k1, qa1, stA[mt], 0, 0, 0);
            stB[mt] = MFMA_BF16(k0, qc0, z, 0, 0, 0);
            stB[mt] = MFMA_BF16(k1, qc1, stB[mt], 0, 0, 0);
        }

        // ---- p = exp2(s*c); per-lane l accumulation; P -> LDS ----
        asm volatile("" ::: "memory");
        #pragma unroll
        for (int mt = 0; mt < 8; mt++) {
            float p0 = __builtin_amdgcn_exp2f(stA[mt][0] * cexp);
            float p1 = __builtin_amdgcn_exp2f(stA[mt][1] * cexp);
            float p2 = __builtin_amdgcn_exp2f(stA[mt][2] * cexp);
            float p3 = __builtin_amdgcn_exp2f(stA[mt][3] * cexp);
            laccA[0] += p0; laccA[1] += p1; laccA[2] += p2; laccA[3] += p3;
            *(uint2*)(ptw + c * 136 + mt * 16 + quad * 4) = pack4_bf16(p0, p1, p2, p3);
        }
        #pragma unroll
        for (int mt = 0; mt < 8; mt++) {
            float p0 = __builtin_amdgcn_exp2f(stB[mt][0] * cexp);
            float p1 = __builtin_amdgcn_exp2f(stB[mt][1] * cexp);
            float p2 = __builtin_amdgcn_exp2f(stB[mt][2] * cexp);
            float p3 = __builtin_amdgcn_exp2f(stB[mt][3] * cexp);
            laccB[0] += p0; laccB[1] += p1; laccB[2] += p2; laccB[3] += p3;
            *(uint2*)(ptw + 2176 + c * 136 + mt * 16 + quad * 4) = pack4_bf16(p0, p1, p2, p3);
        }
        asm volatile("" ::: "memory");

        // ---- O^T += V^T·P^T for BOTH q-tiles; V frags loaded once ----
        #pragma unroll
        for (int ks = 0; ks < 4; ks++) {
            bf16x8 pbA = *(const bf16x8*)(ptw + c * 136 + ks * 32 + quad * 8);
            bf16x8 pbB = *(const bf16x8*)(ptw + 2176 + c * 136 + ks * 32 + quad * 8);
            bf16x8 v0 = va[ks & 1][0], v1 = va[ks & 1][1];
            bf16x8 v2 = va[ks & 1][2], v3 = va[ks & 1][3];
            if (ks < 2) {
                #pragma unroll
                for (int mt = 0; mt < 4; mt++)
                    va[ks & 1][mt] =
                        *(const bf16x8*)(vbase + (size_t)((s0 + ks + 2) * 4 + mt) * 64 * 8);
            }
            oa0 = MFMA_BF16(v0, pbA, oa0, 0, 0, 0);
            oa1 = MFMA_BF16(v1, pbA, oa1, 0, 0, 0);
            oa2 = MFMA_BF16(v2, pbA, oa2, 0, 0, 0);
            oa3 = MFMA_BF16(v3, pbA, oa3, 0, 0, 0);
            ob0 = MFMA_BF16(v0, pbB, ob0, 0, 0, 0);
            ob1 = MFMA_BF16(v1, pbB, ob1, 0, 0, 0);
            ob2 = MFMA_BF16(v2, pbB, ob2, 0, 0, 0);
            ob3 = MFMA_BF16(v3, pbB, ob3, 0, 0, 0);
        }
        asm volatile("" ::: "memory");
    }

    // ---- one l reduction per wave per q-tile ----
    float lA = (laccA[0] + laccA[1]) + (laccA[2] + laccA[3]);
    lA += __shfl_xor(lA, 16);
    lA += __shfl_xor(lA, 32);
    float lB = (laccB[0] + laccB[1]) + (laccB[2] + laccB[3]);
    lB += __shfl_xor(lB, 16);
    lB += __shfl_xor(lB, 32);

    // ---- publish partials: O^T D-layout row=d=mt*16+quad*4+r, col=q=c ----
    *(f32x4*)&obuf[wave][0][c][ 0 + quad * 4] = oa0;
    *(f32x4*)&obuf[wave][0][c][16 + quad * 4] = oa1;
    *(f32x4*)&obuf[wave][0][c][32 + quad * 4] = oa2;
    *(f32x4*)&obuf[wave][0][c][48 + quad * 4] = oa3;
    *(f32x4*)&obuf[wave][1][c][ 0 + quad * 4] = ob0;
    *(f32x4*)&obuf[wave][1][c][16 + quad * 4] = ob1;
    *(f32x4*)&obuf[wave][1][c][32 + quad * 4] = ob2;
    *(f32x4*)&obuf[wave][1][c][48 + quad * 4] = ob3;
    if (quad == 0) { lbuf[wave][0][c] = lA; lbuf[wave][1][c] = lB; }
    __syncthreads();

    // ---- combine 4 key-range partials; 256 thr x 8 floats, coalesced ----
    const int tid = threadIdx.x;
    const int row = tid >> 3;                    // block-local q row (0..31)
    const int d0  = (tid & 7) * 8;               // d base (0..56)
    const int qt  = row >> 4;
    const int r   = row & 15;
    const float L = (lbuf[0][qt][r] + lbuf[1][qt][r]) +
                    (lbuf[2][qt][r] + lbuf[3][qt][r]);
    const float rl = 1.f / L;
    f32x4 Oa = {0,0,0,0}, Ob = {0,0,0,0};
    #pragma unroll
    for (int w = 0; w < 4; w++) {
        f32x4 a = *(const f32x4*)&obuf[w][qt][r][d0];
        f32x4 bfr = *(const f32x4*)&obuf[w][qt][r][d0 + 4];
        Oa[0] += a[0]; Oa[1] += a[1]; Oa[2] += a[2]; Oa[3] += a[3];
        Ob[0] += bfr[0]; Ob[1] += bfr[1]; Ob[2] += bfr[2]; Ob[3] += bfr[3];
    }
    Oa[0] *= rl; Oa[1] *= rl; Oa[2] *= rl; Oa[3] *= rl;
    Ob[0] *= rl; Ob[1] *= rl; Ob[2] *= rl; Ob[3] *= rl;
    float* op = out + (size_t)(tb + row) * 64 + d0;
    *(f32x4*)op       = Oa;
    *(f32x4*)(op + 4) = Ob;
}

// ---------------------------------------------------------------------------
extern "C" void kernel_launch(void* const* d_in, const int* in_sizes, int n_in,
                              void* d_out, int out_size, void* d_ws, size_t ws_size,
                              hipStream_t stream)
{
    const float* x  = (const float*)d_in[0];
    const float* Wk = (const float*)d_in[1];
    const float* Wq = (const float*)d_in[2];
    const float* Wv = (const float*)d_in[3];
    float* out = (float*)d_out;

    char* ws = (char*)d_ws;
    unsigned short* qg  = (unsigned short*)(ws);                  // 2 MiB
    unsigned short* kg2 = (unsigned short*)(ws + (2u << 20));     // 2 MiB
    unsigned short* vg2 = (unsigned short*)(ws + (4u << 20));     // 2 MiB
    unsigned short* wt2 = (unsigned short*)(ws + (6u << 20));     // 192 KiB
    unsigned short* xb2 = (unsigned short*)(ws + (7u << 20));     // 16 MiB

    hipLaunchKernelGGL(prep_kernel, dim3(4144), dim3(256), 0, stream,
                       x, Wq, Wk, Wv, xb2, wt2);
    hipLaunchKernelGGL(proj_kernel, dim3(768),  dim3(256), 0, stream,
                       xb2, wt2, qg, kg2, vg2);
    hipLaunchKernelGGL(attn_kernel, dim3(512),  dim3(256), 0, stream,
                       qg, kg2, vg2, out);
}

// Round 11
// 112.362 us; speedup vs baseline: 1.0176x; 1.0176x over previous
//
#include <hip/hip_runtime.h>
#include <hip/hip_bf16.h>
#include <stdint.h>

// ---------------------------------------------------------------------------
// Head: out = softmax((x Wq)(x Wk)^T / 8) (x Wv)
// B=8, T=2048, C=512, D=64.  ALL I/O FP32; internals bf16 MFMA + fp32 accum.
//
// R11: proj reverted to exact R8 (best: R8 110.2 < R9 113.2 < R10 114.3 --
// W traffic was never the bottleneck; both "fixes" added overhead).
// attn: alias obuf ONTO pt (temporally disjoint per wave: all P reads
// complete before O partials are written; regions per-wave private).
// LDS 70->35 KB => 2->4 blocks/CU => up to 16 waves/CU of latency hiding
// for the K/V L2 streams.
// Keep: frag-order layouts (R6), 2-q-tile attn waves (R8), V-hoist (R9),
// no-max softmax, XCD batch swizzle, launch_bounds(256,1).
//
// MFMA 16x16x32 bf16 fragment maps (gfx950, m89/m91-verified):
//   A: lane holds A[m=lane&15][k=quad*8+j]   (quad=lane>>4, j=0..7)
//   B: lane holds B[k=quad*8+j][n=lane&15]
//   D: lane holds D[row=quad*4+r][col=lane&15] (r=reg 0..3)
//
// Fragment-order chunk layouts (16B chunks, chunk's 8 elems = j=0..7):
//   xb2: chunk[((tt*16+ks)*4+quad)*16+c] = x[tt*16+c][ks*32+quad*8+j]
//   wt2: chunk[(((w*4+mt)*16+ks)*4+quad)*16+c] = W_w[ks*32+quad*8+j][mt*16+c]
//   kg2: chunk[b*16384 + ((g*2+h)*4+quad)*16+c] = K[b][g*16+c][h*32+quad*8+j]
//   vg2: chunk[b*16384 + ((s*4+mt)*4+quad)*16+c] = V[b][s*32+quad*8+j][mt*16+c]
// ---------------------------------------------------------------------------

typedef short bf16x8 __attribute__((ext_vector_type(8)));
typedef float f32x4 __attribute__((ext_vector_type(4)));

#define MFMA_BF16 __builtin_amdgcn_mfma_f32_16x16x32_bf16

__device__ __forceinline__ unsigned int pk2(float a, float b) {
    __hip_bfloat162 h = __float22bfloat162_rn(float2{a, b});   // v_cvt_pk_bf16_f32
    union { __hip_bfloat162 h; unsigned int u; } r; r.h = h;
    return r.u;
}

__device__ __forceinline__ uint2 pack4_bf16(float a, float b, float c, float d) {
    uint2 r; r.x = pk2(a, b); r.y = pk2(c, d); return r;
}

__device__ __forceinline__ bf16x8 cvt8(f32x4 a, f32x4 b) {
    union { bf16x8 v; unsigned int u[4]; } r;
    r.u[0] = pk2(a[0], a[1]); r.u[1] = pk2(a[2], a[3]);
    r.u[2] = pk2(b[0], b[1]); r.u[3] = pk2(b[2], b[3]);
    return r.v;
}

__device__ __forceinline__ unsigned short bf1(float a) {
    __hip_bfloat16 h = __float2bfloat16(a);
    union { __hip_bfloat16 h; unsigned short u; } r; r.h = h;
    return r.u;
}

// ---------------------------------------------------------------------------
// Kernel 0: prep = wt (blocks 0..47) + xconv (blocks 48..4143).
// ---------------------------------------------------------------------------
__global__ void prep_kernel(const float* __restrict__ x,
                            const float* __restrict__ Wq,
                            const float* __restrict__ Wk,
                            const float* __restrict__ Wv,
                            unsigned short* __restrict__ xb2,
                            unsigned short* __restrict__ wt2)
{
    if (blockIdx.x < 48) {
        int id = blockIdx.x * 256 + threadIdx.x;      // 12288 = 3*4*16*4*16
        int c    = id & 15;
        int quad = (id >> 4) & 3;
        int ks   = (id >> 6) & 15;
        int mt   = (id >> 10) & 3;
        int w    = id >> 12;
        const float* src = (w == 0) ? Wq : ((w == 1) ? Wk : Wv);
        const int n  = mt * 16 + c;
        const int k0 = ks * 32 + quad * 8;
        unsigned short* dst = wt2 + (size_t)id * 8;
        #pragma unroll
        for (int j = 0; j < 8; j++)
            dst[j] = bf1(src[(size_t)(k0 + j) * 64 + n]);
        return;
    }
    int i = (blockIdx.x - 48) * 256 + threadIdx.x;    // i = tok*64 + dblock
    int tok    = i >> 6;
    int dblock = i & 63;
    f32x4 a = *(const f32x4*)(x + (size_t)i * 8);
    f32x4 b = *(const f32x4*)(x + (size_t)i * 8 + 4);
    int tt = tok >> 4, c = tok & 15;
    int ks = dblock >> 2, quad = dblock & 3;
    size_t chunk = ((size_t)(tt * 16 + ks) * 4 + quad) * 16 + c;
    *(bf16x8*)(xb2 + chunk * 8) = cvt8(a, b);
}

// ---------------------------------------------------------------------------
// Kernel 1: projections (exact R8 form -- best measured). One wave = 16
// tokens x one matrix; both operands fragment-order from global (1KB/load).
// 768 blocks x 4 waves = 3072 waves -> 12 waves/CU.
// ---------------------------------------------------------------------------
__global__ __launch_bounds__(256, 1) void proj_kernel(
    const unsigned short* __restrict__ xb2, const unsigned short* __restrict__ wt2,
    unsigned short* __restrict__ qg, unsigned short* __restrict__ kg2,
    unsigned short* __restrict__ vg2)
{
    const int lane = threadIdx.x & 63;
    const int c    = lane & 15;
    const int quad = lane >> 4;
    const int wave = threadIdx.x >> 6;
    const int gw   = blockIdx.x * 4 + wave;   // 0..3071
    const int w    = gw % 3;                  // matrix: 0:q 1:k 2:v
    const int tt   = gw / 3;                  // token tile 0..1023
    const int t0   = tt * 16;

    f32x4 acc[4];
    #pragma unroll
    for (int i = 0; i < 4; i++) acc[i] = f32x4{0.f, 0.f, 0.f, 0.f};

    const unsigned short* xbase = xb2 + ((size_t)tt * 1024 + lane) * 8;
    const unsigned short* wbase = wt2 + ((size_t)w * 4096 + lane) * 8;

    #pragma unroll 4
    for (int ks = 0; ks < 16; ks++) {
        bf16x8 xf = *(const bf16x8*)(xbase + (size_t)ks * 512);
        #pragma unroll
        for (int mt = 0; mt < 4; mt++) {
            bf16x8 wa = *(const bf16x8*)(wbase + ((size_t)mt * 16 + ks) * 512);
            acc[mt] = MFMA_BF16(wa, xf, acc[mt], 0, 0, 0);
        }
    }

    const int b  = t0 >> 11;             // batch
    const int tb = t0 & 2047;            // batch-local tile base

    if (w == 0) {
        unsigned short* base = qg + (size_t)(t0 + c) * 64;
        #pragma unroll
        for (int mt = 0; mt < 4; mt++)
            *(uint2*)(base + mt * 16 + quad * 4) =
                pack4_bf16(acc[mt][0], acc[mt][1], acc[mt][2], acc[mt][3]);
    } else if (w == 1) {
        const int g = tb >> 4;
        #pragma unroll
        for (int mt = 0; mt < 4; mt++) {
            const int h  = mt >> 1;
            const int qk = (mt & 1) * 2 + (quad >> 1);
            size_t chunk = (size_t)b * 16384 + ((size_t)(g * 2 + h) * 4 + qk) * 16 + c;
            *(uint2*)(kg2 + chunk * 8 + (quad & 1) * 4) =
                pack4_bf16(acc[mt][0], acc[mt][1], acc[mt][2], acc[mt][3]);
        }
    } else {
        const int tk = tb + c;
        const int s  = tk >> 5;
        const int qv = (tk >> 3) & 3;
        const int j  = tk & 7;
        #pragma unroll
        for (int mt = 0; mt < 4; mt++) {
            size_t chunk = (size_t)b * 16384 + ((size_t)(s * 4 + mt) * 4 + qv) * 16 + quad * 4;
            unsigned short* dst = vg2 + chunk * 8 + j;
            dst[0]  = bf1(acc[mt][0]);
            dst[8]  = bf1(acc[mt][1]);
            dst[16] = bf1(acc[mt][2]);
            dst[24] = bf1(acc[mt][3]);
        }
    }
}

// ---------------------------------------------------------------------------
// Kernel 2: flash attention, 2 q-tiles/wave, V-hoist, obuf ALIASED onto pt.
// Per wave: all P (pt) reads finish (last PV MFMA) before O partials are
// written into the same per-wave LDS region -- temporally disjoint, fences
// bracket the boundary. LDS ~35 KB -> 4 blocks/CU. 512 blocks x 256 thr.
// ---------------------------------------------------------------------------
__global__ __launch_bounds__(256, 1) void attn_kernel(
    const unsigned short* __restrict__ qg, const unsigned short* __restrict__ kg2,
    const unsigned short* __restrict__ vg2, float* __restrict__ out)
{
    __shared__ unsigned short pt[4][2][2176];      // [wave][qtile][q*136] P bufs
    __shared__ float lbuf[4][2][16];
    // obuf aliased onto pt: per-wave 8704B region (2*16*68*4 == 2*2176*2).
    float (*obuf)[2][16][68] = (float (*)[2][16][68])(void*)pt;

    const int lane = threadIdx.x & 63;
    const int wave = threadIdx.x >> 6;
    const int c    = lane & 15;
    const int quad = lane >> 4;
    const int b    = blockIdx.x & 7;             // batch -> XCD (L2 locality)
    const int g    = blockIdx.x >> 3;            // 32-row group (0..63)
    const int tb   = b * 2048 + g * 32;          // block q base

    unsigned short* ptw = &pt[wave][0][0];
    const unsigned short* kbase = kg2 + ((size_t)b * 16384 + lane) * 8;
    const unsigned short* vbase = vg2 + ((size_t)b * 16384 + lane) * 8;

    // Q frags for both q-tiles
    bf16x8 qa0 = *(const bf16x8*)(qg + (size_t)(tb + c) * 64 + quad * 8);
    bf16x8 qa1 = *(const bf16x8*)(qg + (size_t)(tb + c) * 64 + 32 + quad * 8);
    bf16x8 qc0 = *(const bf16x8*)(qg + (size_t)(tb + 16 + c) * 64 + quad * 8);
    bf16x8 qc1 = *(const bf16x8*)(qg + (size_t)(tb + 16 + c) * 64 + 32 + quad * 8);

    f32x4 oa0 = {0,0,0,0}, oa1 = {0,0,0,0}, oa2 = {0,0,0,0}, oa3 = {0,0,0,0};
    f32x4 ob0 = {0,0,0,0}, ob1 = {0,0,0,0}, ob2 = {0,0,0,0}, ob3 = {0,0,0,0};
    f32x4 laccA = {0,0,0,0}, laccB = {0,0,0,0};
    const float cexp = 0.18033688011112042f;   // log2(e)/8  (scores = raw/8)

    for (int kt = wave * 4; kt < wave * 4 + 4; kt++) {
        const int key0 = kt * 128;
        const int g0   = key0 >> 4;              // 16-key group base
        const int s0   = key0 >> 5;              // 32-key block base

        // ---- V ks=0,1 preloads FIRST: latency hides under S MFMAs + exp ----
        bf16x8 va[2][4];
        #pragma unroll
        for (int mt = 0; mt < 4; mt++) {
            va[0][mt] = *(const bf16x8*)(vbase + (size_t)((s0    ) * 4 + mt) * 64 * 8);
            va[1][mt] = *(const bf16x8*)(vbase + (size_t)((s0 + 1) * 4 + mt) * 64 * 8);
        }

        // ---- S^T = K·Q^T for BOTH q-tiles; K frags loaded once ----
        f32x4 stA[8], stB[8];
        const f32x4 z = {0,0,0,0};
        #pragma unroll
        for (int mt = 0; mt < 8; mt++) {
            bf16x8 k0 = *(const bf16x8*)(kbase + (size_t)((g0 + mt) * 2    ) * 64 * 8);
            bf16x8 k1 = *(const bf16x8*)(kbase + (size_t)((g0 + mt) * 2 + 1) * 64 * 8);
            stA[mt] = MFMA_BF16(k0, qa0, z, 0, 0, 0);
            stA[mt] = MFMA_BF16(k1, qa1, stA[mt], 0, 0, 0);
            stB[mt] = MFMA_BF16(k0, qc0, z, 0, 0, 0);
            stB[mt] = MFMA_BF16(k1, qc1, stB[mt], 0, 0, 0);
        }

        // ---- p = exp2(s*c); per-lane l accumulation; P -> LDS ----
        asm volatile("" ::: "memory");
        #pragma unroll
        for (int mt = 0; mt < 8; mt++) {
            float p0 = __builtin_amdgcn_exp2f(stA[mt][0] * cexp);
            float p1 = __builtin_amdgcn_exp2f(stA[mt][1] * cexp);
            float p2 = __builtin_amdgcn_exp2f(stA[mt][2] * cexp);
            float p3 = __builtin_amdgcn_exp2f(stA[mt][3] * cexp);
            laccA[0] += p0; laccA[1] += p1; laccA[2] += p2; laccA[3] += p3;
            *(uint2*)(ptw + c * 136 + mt * 16 + quad * 4) = pack4_bf16(p0, p1, p2, p3);
        }
        #pragma unroll
        for (int mt = 0; mt < 8; mt++) {
            float p0 = __builtin_amdgcn_exp2f(stB[mt][0] * cexp);
            float p1 = __builtin_amdgcn_exp2f(stB[mt][1] * cexp);
            float p2 = __builtin_amdgcn_exp2f(stB[mt][2] * cexp);
            float p3 = __builtin_amdgcn_exp2f(stB[mt][3] * cexp);
            laccB[0] += p0; laccB[1] += p1; laccB[2] += p2; laccB[3] += p3;
            *(uint2*)(ptw + 2176 + c * 136 + mt * 16 + quad * 4) = pack4_bf16(p0, p1, p2, p3);
        }
        asm volatile("" ::: "memory");

        // ---- O^T += V^T·P^T for BOTH q-tiles; V frags loaded once ----
        #pragma unroll
        for (int ks = 0; ks < 4; ks++) {
            bf16x8 pbA = *(const bf16x8*)(ptw + c * 136 + ks * 32 + quad * 8);
            bf16x8 pbB = *(const bf16x8*)(ptw + 2176 + c * 136 + ks * 32 + quad * 8);
            bf16x8 v0 = va[ks & 1][0], v1 = va[ks & 1][1];
            bf16x8 v2 = va[ks & 1][2], v3 = va[ks & 1][3];
            if (ks < 2) {
                #pragma unroll
                for (int mt = 0; mt < 4; mt++)
                    va[ks & 1][mt] =
                        *(const bf16x8*)(vbase + (size_t)((s0 + ks + 2) * 4 + mt) * 64 * 8);
            }
            oa0 = MFMA_BF16(v0, pbA, oa0, 0, 0, 0);
            oa1 = MFMA_BF16(v1, pbA, oa1, 0, 0, 0);
            oa2 = MFMA_BF16(v2, pbA, oa2, 0, 0, 0);
            oa3 = MFMA_BF16(v3, pbA, oa3, 0, 0, 0);
            ob0 = MFMA_BF16(v0, pbB, ob0, 0, 0, 0);
            ob1 = MFMA_BF16(v1, pbB, ob1, 0, 0, 0);
            ob2 = MFMA_BF16(v2, pbB, ob2, 0, 0, 0);
            ob3 = MFMA_BF16(v3, pbB, ob3, 0, 0, 0);
        }
        asm volatile("" ::: "memory");
    }

    // ---- one l reduction per wave per q-tile ----
    float lA = (laccA[0] + laccA[1]) + (laccA[2] + laccA[3]);
    lA += __shfl_xor(lA, 16);
    lA += __shfl_xor(lA, 32);
    float lB = (laccB[0] + laccB[1]) + (laccB[2] + laccB[3]);
    lB += __shfl_xor(lB, 16);
    lB += __shfl_xor(lB, 32);

    // ---- publish partials into the ALIASED region (all P reads done) ----
    asm volatile("" ::: "memory");
    *(f32x4*)&obuf[wave][0][c][ 0 + quad * 4] = oa0;
    *(f32x4*)&obuf[wave][0][c][16 + quad * 4] = oa1;
    *(f32x4*)&obuf[wave][0][c][32 + quad * 4] = oa2;
    *(f32x4*)&obuf[wave][0][c][48 + quad * 4] = oa3;
    *(f32x4*)&obuf[wave][1][c][ 0 + quad * 4] = ob0;
    *(f32x4*)&obuf[wave][1][c][16 + quad * 4] = ob1;
    *(f32x4*)&obuf[wave][1][c][32 + quad * 4] = ob2;
    *(f32x4*)&obuf[wave][1][c][48 + quad * 4] = ob3;
    if (quad == 0) { lbuf[wave][0][c] = lA; lbuf[wave][1][c] = lB; }
    __syncthreads();

    // ---- combine 4 key-range partials; 256 thr x 8 floats, coalesced ----
    const int tid = threadIdx.x;
    const int row = tid >> 3;                    // block-local q row (0..31)
    const int d0  = (tid & 7) * 8;               // d base (0..56)
    const int qt  = row >> 4;
    const int r   = row & 15;
    const float L = (lbuf[0][qt][r] + lbuf[1][qt][r]) +
                    (lbuf[2][qt][r] + lbuf[3][qt][r]);
    const float rl = 1.f / L;
    f32x4 Oa = {0,0,0,0}, Ob = {0,0,0,0};
    #pragma unroll
    for (int w = 0; w < 4; w++) {
        f32x4 a = *(const f32x4*)&obuf[w][qt][r][d0];
        f32x4 bfr = *(const f32x4*)&obuf[w][qt][r][d0 + 4];
        Oa[0] += a[0]; Oa[1] += a[1]; Oa[2] += a[2]; Oa[3] += a[3];
        Ob[0] += bfr[0]; Ob[1] += bfr[1]; Ob[2] += bfr[2]; Ob[3] += bfr[3];
    }
    Oa[0] *= rl; Oa[1] *= rl; Oa[2] *= rl; Oa[3] *= rl;
    Ob[0] *= rl; Ob[1] *= rl; Ob[2] *= rl; Ob[3] *= rl;
    float* op = out + (size_t)(tb + row) * 64 + d0;
    *(f32x4*)op       = Oa;
    *(f32x4*)(op + 4) = Ob;
}

// ---------------------------------------------------------------------------
extern "C" void kernel_launch(void* const* d_in, const int* in_sizes, int n_in,
                              void* d_out, int out_size, void* d_ws, size_t ws_size,
                              hipStream_t stream)
{
    const float* x  = (const float*)d_in[0];
    const float* Wk = (const float*)d_in[1];
    const float* Wq = (const float*)d_in[2];
    const float* Wv = (const float*)d_in[3];
    float* out = (float*)d_out;

    char* ws = (char*)d_ws;
    unsigned short* qg  = (unsigned short*)(ws);                  // 2 MiB
    unsigned short* kg2 = (unsigned short*)(ws + (2u << 20));     // 2 MiB
    unsigned short* vg2 = (unsigned short*)(ws + (4u << 20));     // 2 MiB
    unsigned short* wt2 = (unsigned short*)(ws + (6u << 20));     // 192 KiB
    unsigned short* xb2 = (unsigned short*)(ws + (7u << 20));     // 16 MiB

    hipLaunchKernelGGL(prep_kernel, dim3(4144), dim3(256), 0, stream,
                       x, Wq, Wk, Wv, xb2, wt2);
    hipLaunchKernelGGL(proj_kernel, dim3(768),  dim3(256), 0, stream,
                       xb2, wt2, qg, kg2, vg2);
    hipLaunchKernelGGL(attn_kernel, dim3(512),  dim3(256), 0, stream,
                       qg, kg2, vg2, out);
}